// Round 2
// baseline (287.795 us; speedup 1.0000x reference)
//
#include <hip/hip_runtime.h>

typedef __attribute__((ext_vector_type(8))) __bf16 bf16x8;
typedef __attribute__((ext_vector_type(8))) unsigned short us8;
typedef __attribute__((ext_vector_type(4))) float f32x4;

#define NB 16
#define B_TOTAL 131072
#define SST 36            // nq s-stride (floats): banks +4 per s, conflict-friendly
#define BST 580           // nq b-stride (floats) = 16*36+4: banks +4 per b

__device__ __forceinline__ unsigned short f2bf(float f) {
  union { float f; unsigned int u; } c; c.f = f;
  unsigned int u = c.u;
  u += 0x7fffu + ((u >> 16) & 1u);   // RNE
  return (unsigned short)(u >> 16);
}
__device__ __forceinline__ bf16x8 as_bf(us8 v) {
  union { us8 u; bf16x8 b; } c; c.u = v; return c.b;
}
__device__ __forceinline__ float fast_tanh(float x) {
  float t = __expf(2.0f * x);        // inf-safe: 1-2/inf=1, 1-2/1=-1
  return 1.0f - 2.0f / (t + 1.0f);
}

// ---------------- prep: pre-arrange B-fragments (bf16) into ws -----------------
// rwfrag[s][kh][lane][e] = rw[h=(lane>>4)*8+e][k=kh*16+(lane&15)][s]
// qwfrag[s][kh][lane<16][e] = qw[i=e][h=kh*16+lane][s]
// dgfrag[kh][lane][e] = (h==k) ? bf16(1 - 0.1/tau[k]) : 0
__global__ void shq_prep(const float* __restrict__ qw, const float* __restrict__ rw,
                         const float* __restrict__ tau,
                         unsigned short* __restrict__ rwfrag,
                         unsigned short* __restrict__ qwfrag,
                         unsigned short* __restrict__ dgfrag) {
  int g = blockIdx.x * 256 + threadIdx.x;
  if (g < 2048) {                       // 16 s * 2 kh * 64 lanes
    int s = g >> 7, kh = (g >> 6) & 1, ln = g & 63;
    int k = kh * 16 + (ln & 15), h0 = (ln >> 4) * 8;
    us8 v;
#pragma unroll
    for (int e = 0; e < 8; ++e) v[e] = f2bf(rw[((h0 + e) * 32 + k) * 16 + s]);
    *(us8*)(rwfrag + g * 8) = v;
  } else if (g < 2560) {                // 16 s * 2 kh * 16 lanes
    int j = g - 2048;
    int s = j >> 5, kh = (j >> 4) & 1, ln = j & 15;
    int hc = kh * 16 + ln;
    us8 v;
#pragma unroll
    for (int e = 0; e < 8; ++e) v[e] = f2bf(qw[(e * 32 + hc) * 16 + s]);
    *(us8*)(qwfrag + j * 8) = v;
  } else if (g < 2688) {                // 2 kh * 64 lanes
    int j = g - 2560;
    int kh = (j >> 6) & 1, ln = j & 63;
    int k = kh * 16 + (ln & 15), h0 = (ln >> 4) * 8;
    unsigned short ab = f2bf(1.0f - 0.1f / tau[k]);
    us8 v;
#pragma unroll
    for (int e = 0; e < 8; ++e) v[e] = (h0 + e == k) ? ab : (unsigned short)0;
    *(us8*)(dgfrag + j * 8) = v;
  }
}

// ---------------- main kernel: 512 threads = 16 batch rows ----------------
__global__ __launch_bounds__(512, 8) void shq_main(
    const float* __restrict__ x, const float* __restrict__ hq_g,
    const float* __restrict__ syn, const float* __restrict__ corr,
    const unsigned short* __restrict__ rwfrag,
    const unsigned short* __restrict__ qwfrag,
    const unsigned short* __restrict__ dgfrag,
    float* __restrict__ out) {
  // Time-multiplexed buffer:
  //   [barA, barB): hqT bf16 [s][b][h], strides s:640, b:40 shorts (20.5 KB)
  //   [barB, end):  nq   f32 [b][s][h], strides b:BST, s:SST floats (37.1 KB)
  __shared__ float smem[16 * BST];
  __shared__ float lds_pi[NB * 16 * 2];   // (prob, inv_norm) per (b,s)
  unsigned short* hqT = (unsigned short*)smem;

  const int tid = threadIdx.x;
  const int b0 = blockIdx.x * NB;
  const int lane = tid & 63;
  const int w = tid >> 6;     // wave id: owns s = 2w, 2w+1

  us8 z8 = {0, 0, 0, 0, 0, 0, 0, 0};

  // ---- prologue: x row (bf16 A-frag) + diag B-frags ----
  us8 xu = z8;
  if (lane < 16) {
    const float* xb = x + (size_t)(b0 + lane) * 8;
    f32x4 a = *(const f32x4*)xb, b = *(const f32x4*)(xb + 4);
    xu[0] = f2bf(a[0]); xu[1] = f2bf(a[1]); xu[2] = f2bf(a[2]); xu[3] = f2bf(a[3]);
    xu[4] = f2bf(b[0]); xu[5] = f2bf(b[1]); xu[6] = f2bf(b[2]); xu[7] = f2bf(b[3]);
  }
  us8 dg0 = *(const us8*)(dgfrag + lane * 8);
  us8 dg1 = *(const us8*)(dgfrag + (64 + lane) * 8);

  // ---- phase 1: thread=(bl,h): syndrome -> mask -> correction -> hqT ----
  {
    const int bl = tid >> 5, hh = tid & 31;
    const float* hb = hq_g + (((size_t)(b0 + bl) * 32) + hh) * 16;
    f32x4 h0 = *(const f32x4*)(hb), h1 = *(const f32x4*)(hb + 4);
    f32x4 h2 = *(const f32x4*)(hb + 8), h3 = *(const f32x4*)(hb + 12);
    float hrow[16];
#pragma unroll
    for (int q = 0; q < 4; ++q) {
      hrow[0 + q] = h0[q]; hrow[4 + q] = h1[q]; hrow[8 + q] = h2[q]; hrow[12 + q] = h3[q];
    }
    float sd[4];
#pragma unroll
    for (int c = 0; c < 4; ++c) {
      float a = 0.f;
#pragma unroll
      for (int s = 0; s < 16; ++s) a = fmaf(hrow[s], syn[c * 16 + s], a);
      sd[c] = (fabsf(a) > 0.01f) ? a : 0.f;
    }
#pragma unroll
    for (int s = 0; s < 16; ++s) {
      float cs = sd[0] * corr[s] + sd[1] * corr[16 + s] + sd[2] * corr[32 + s] + sd[3] * corr[48 + s];
      hqT[s * 640 + bl * 40 + hh] = f2bf(hrow[s] - cs);
    }
  }
  __syncthreads();   // A: hqT ready

  // ---- phase 2a: pull A-frags (hq) out of hqT before it is clobbered ----
  us8 hq_u[2];
#pragma unroll
  for (int sl = 0; sl < 2; ++sl)
    hq_u[sl] = *(const us8*)&hqT[(2 * w + sl) * 640 + (lane & 15) * 40 + (lane >> 4) * 8];
  __syncthreads();   // B: hqT dead, nq region free

  // ---- phase 2b: MFMA rec+inp+decay per (s, khalf); write new_q f32 ----
  {
    f32x4 zro = {0.f, 0.f, 0.f, 0.f};
#pragma unroll
    for (int sl = 0; sl < 2; ++sl) {
      int s = 2 * w + sl;
      us8 rw0 = *(const us8*)(rwfrag + ((s * 2 + 0) * 64 + lane) * 8);
      us8 rw1 = *(const us8*)(rwfrag + ((s * 2 + 1) * 64 + lane) * 8);
      us8 qw0 = (lane < 16) ? *(const us8*)(qwfrag + ((s * 2 + 0) * 16 + lane) * 8) : z8;
      us8 qw1 = (lane < 16) ? *(const us8*)(qwfrag + ((s * 2 + 1) * 16 + lane) * 8) : z8;
      bf16x8 hqf = as_bf(hq_u[sl]);
#pragma unroll
      for (int kh = 0; kh < 2; ++kh) {
        f32x4 acc = __builtin_amdgcn_mfma_f32_16x16x32_bf16(as_bf(xu), as_bf(kh ? qw1 : qw0), zro, 0, 0, 0);
        acc = __builtin_amdgcn_mfma_f32_16x16x32_bf16(hqf, as_bf(kh ? rw1 : rw0), acc, 0, 0, 0);
        f32x4 na;
#pragma unroll
        for (int r = 0; r < 4; ++r) na[r] = 0.1f * fast_tanh(acc[r]);
        na = __builtin_amdgcn_mfma_f32_16x16x32_bf16(hqf, as_bf(kh ? dg1 : dg0), na, 0, 0, 0);
        int k = kh * 16 + (lane & 15);
#pragma unroll
        for (int r = 0; r < 4; ++r) {
          int br = (lane >> 4) * 4 + r;
          smem[br * BST + s * SST + k] = na[r];
        }
      }
    }
  }
  __syncthreads();   // C: nq ready

  // ---- phase 3a: thread=(b,s): stream stable, reduce norms, write pi ----
  if (tid < 256) {
    int b3 = tid >> 4, s3 = tid & 15;
    int base = b3 * BST + s3 * SST;
    float ssq = 0.f, sab = 0.f;
    f32x4 zv = {0.f, 0.f, 0.f, 0.f};
#pragma unroll
    for (int q = 0; q < 8; ++q) {
      f32x4 c0 = *(const f32x4*)&smem[base + 4 * q];
      f32x4 cm = (s3 > 0)  ? *(const f32x4*)&smem[base - SST + 4 * q] : zv;
      f32x4 cp = (s3 < 15) ? *(const f32x4*)&smem[base + SST + 4 * q] : zv;
#pragma unroll
      for (int e = 0; e < 4; ++e) {
        float st = fmaf(0.04f * c0[e], cm[e] + cp[e], c0[e]);
        ssq = fmaf(st, st, ssq);
        sab += fabsf(st);
      }
    }
    float inv = __fdividef(1.0f, sqrtf(ssq) + 1e-8f);
    float energy = ssq * inv * inv;
    float mag = sab * inv;
    float pu = __fdividef(mag, energy + 1e-6f);
    float psum = pu;
#pragma unroll
    for (int m = 1; m < 16; m <<= 1) psum += __shfl_xor(psum, m, 16);
    lds_pi[(b3 * 16 + s3) * 2 + 0] = __fdividef(pu, psum);
    lds_pi[(b3 * 16 + s3) * 2 + 1] = inv;
  }
  __syncthreads();   // D: pi ready (nq untouched)

  // ---- phase 3b: thread=(b,h): recompute stable column, q_norm + output ----
  {
    const int b3 = tid >> 5, h3 = tid & 31;
    float col[16];
#pragma unroll
    for (int s = 0; s < 16; ++s) col[s] = smem[b3 * BST + s * SST + h3];
    float cc[15];
#pragma unroll
    for (int s = 0; s < 15; ++s) cc[s] = 0.4f * col[s] * col[s + 1];
    float oacc = 0.f;
    float qn[16];
#pragma unroll
    for (int s = 0; s < 16; ++s) {
      float ent = ((s > 0) ? cc[s - 1] : 0.f) + ((s < 15) ? cc[s] : 0.f);
      float st = fmaf(0.1f, ent, col[s]);
      float2 pv = *(const float2*)&lds_pi[(b3 * 16 + s) * 2];
      float q = st * pv.y;
      qn[s] = q;
      oacc = fmaf(q, pv.x, oacc);
    }
    out[(size_t)(b0 + b3) * 32 + h3] = oacc;
    float* qp = out + 4194304 + (((size_t)(b0 + b3) * 32) + h3) * 16;
    f32x4 q0 = {qn[0], qn[1], qn[2], qn[3]};
    f32x4 q1 = {qn[4], qn[5], qn[6], qn[7]};
    f32x4 q2 = {qn[8], qn[9], qn[10], qn[11]};
    f32x4 q3 = {qn[12], qn[13], qn[14], qn[15]};
    *(f32x4*)(qp) = q0; *(f32x4*)(qp + 4) = q1;
    *(f32x4*)(qp + 8) = q2; *(f32x4*)(qp + 12) = q3;
  }
}

extern "C" void kernel_launch(void* const* d_in, const int* in_sizes, int n_in,
                              void* d_out, int out_size, void* d_ws, size_t ws_size,
                              hipStream_t stream) {
  const float* x    = (const float*)d_in[0];
  const float* hq   = (const float*)d_in[1];
  const float* qw   = (const float*)d_in[2];
  const float* rw   = (const float*)d_in[3];
  const float* tau  = (const float*)d_in[4];
  const float* syn  = (const float*)d_in[5];
  const float* corr = (const float*)d_in[6];
  unsigned short* ws = (unsigned short*)d_ws;
  unsigned short* rwfrag = ws;            // 16384 shorts
  unsigned short* qwfrag = ws + 16384;    // 4096 shorts
  unsigned short* dgfrag = ws + 20480;    // 1024 shorts
  shq_prep<<<11, 256, 0, stream>>>(qw, rw, tau, rwfrag, qwfrag, dgfrag);
  shq_main<<<B_TOTAL / NB, 512, 0, stream>>>(x, hq, syn, corr, rwfrag, qwfrag, dgfrag, (float*)d_out);
}

// Round 3
// 153.786 us; speedup vs baseline: 1.8714x; 1.8714x over previous
//
#include <hip/hip_runtime.h>

typedef __attribute__((ext_vector_type(8))) __bf16 bf16x8;
typedef __attribute__((ext_vector_type(8))) unsigned short us8;
typedef __attribute__((ext_vector_type(4))) float f32x4;

#define NB 16
#define B_TOTAL 131072
#define SST 36            // nq s-stride (floats)
#define BST 580           // nq b-stride (floats) = 16*36+4

__device__ __forceinline__ unsigned short f2bf(float f) {
  union { float f; unsigned int u; } c; c.f = f;
  unsigned int u = c.u;
  u += 0x7fffu + ((u >> 16) & 1u);   // RNE
  return (unsigned short)(u >> 16);
}
__device__ __forceinline__ bf16x8 as_bf(us8 v) {
  union { us8 u; bf16x8 b; } c; c.u = v; return c.b;
}
__device__ __forceinline__ float fast_tanh(float x) {
  float t = __expf(2.0f * x);        // inf-safe: 1-2/inf=1, 1-2/1=-1
  return 1.0f - 2.0f / (t + 1.0f);
}

// ---------------- prep: pre-arrange B-fragments (bf16) into ws -----------------
__global__ void shq_prep(const float* __restrict__ qw, const float* __restrict__ rw,
                         const float* __restrict__ tau,
                         unsigned short* __restrict__ rwfrag,
                         unsigned short* __restrict__ qwfrag,
                         unsigned short* __restrict__ dgfrag) {
  int g = blockIdx.x * 256 + threadIdx.x;
  if (g < 2048) {                       // 16 s * 2 kh * 64 lanes
    int s = g >> 7, kh = (g >> 6) & 1, ln = g & 63;
    int k = kh * 16 + (ln & 15), h0 = (ln >> 4) * 8;
    us8 v;
#pragma unroll
    for (int e = 0; e < 8; ++e) v[e] = f2bf(rw[((h0 + e) * 32 + k) * 16 + s]);
    *(us8*)(rwfrag + g * 8) = v;
  } else if (g < 2560) {                // 16 s * 2 kh * 16 lanes
    int j = g - 2048;
    int s = j >> 5, kh = (j >> 4) & 1, ln = j & 15;
    int hc = kh * 16 + ln;
    us8 v;
#pragma unroll
    for (int e = 0; e < 8; ++e) v[e] = f2bf(qw[(e * 32 + hc) * 16 + s]);
    *(us8*)(qwfrag + j * 8) = v;
  } else if (g < 2688) {                // 2 kh * 64 lanes
    int j = g - 2560;
    int kh = (j >> 6) & 1, ln = j & 63;
    int k = kh * 16 + (ln & 15), h0 = (ln >> 4) * 8;
    unsigned short ab = f2bf(1.0f - 0.1f / tau[k]);
    us8 v;
#pragma unroll
    for (int e = 0; e < 8; ++e) v[e] = (h0 + e == k) ? ab : (unsigned short)0;
    *(us8*)(dgfrag + j * 8) = v;
  }
}

// ---------------- main kernel: 512 threads = 16 batch rows ----------------
__global__ __launch_bounds__(512, 4) void shq_main(
    const float* __restrict__ x, const float* __restrict__ hq_g,
    const float* __restrict__ syn, const float* __restrict__ corr,
    const unsigned short* __restrict__ rwfrag,
    const unsigned short* __restrict__ qwfrag,
    const unsigned short* __restrict__ dgfrag,
    float* __restrict__ out) {
  // Time-multiplexed buffer:
  //   [barA, barB): hqT bf16 [s][b][h], strides s:640, b:40 shorts (20.5 KB)
  //   [barB, end):  nq   f32 [b][s][h], strides b:BST, s:SST floats (37.1 KB)
  __shared__ float smem[16 * BST];
  __shared__ float2 lds_pi[NB * 16];   // (prob, inv_norm) per (b,s)
  unsigned short* hqT = (unsigned short*)smem;

  const int tid = threadIdx.x;
  const int b0 = blockIdx.x * NB;
  const int lane = tid & 63;
  const int w = tid >> 6;     // wave id: owns s = 2w, 2w+1

  us8 z8 = {0, 0, 0, 0, 0, 0, 0, 0};

  // ---- prologue: x row (bf16 A-frag) ----
  us8 xu = z8;
  if (lane < 16) {
    const float* xb = x + (size_t)(b0 + lane) * 8;
    f32x4 a = *(const f32x4*)xb, b = *(const f32x4*)(xb + 4);
    xu[0] = f2bf(a[0]); xu[1] = f2bf(a[1]); xu[2] = f2bf(a[2]); xu[3] = f2bf(a[3]);
    xu[4] = f2bf(b[0]); xu[5] = f2bf(b[1]); xu[6] = f2bf(b[2]); xu[7] = f2bf(b[3]);
  }

  // ---- phase 1: thread=(bl,h): syndrome -> mask -> correction -> hqT ----
  {
    const int bl = tid >> 5, hh = tid & 31;
    const float* hb = hq_g + (((size_t)(b0 + bl) * 32) + hh) * 16;
    f32x4 h0 = *(const f32x4*)(hb), h1 = *(const f32x4*)(hb + 4);
    f32x4 h2 = *(const f32x4*)(hb + 8), h3 = *(const f32x4*)(hb + 12);
    float hrow[16];
#pragma unroll
    for (int q = 0; q < 4; ++q) {
      hrow[0 + q] = h0[q]; hrow[4 + q] = h1[q]; hrow[8 + q] = h2[q]; hrow[12 + q] = h3[q];
    }
    float sd[4];
#pragma unroll
    for (int c = 0; c < 4; ++c) {
      float a = 0.f;
#pragma unroll
      for (int s = 0; s < 16; ++s) a = fmaf(hrow[s], syn[c * 16 + s], a);
      sd[c] = (fabsf(a) > 0.01f) ? a : 0.f;
    }
#pragma unroll
    for (int s = 0; s < 16; ++s) {
      float cs = sd[0] * corr[s] + sd[1] * corr[16 + s] + sd[2] * corr[32 + s] + sd[3] * corr[48 + s];
      hqT[s * 640 + bl * 40 + hh] = f2bf(hrow[s] - cs);
    }
  }
  __syncthreads();   // A: hqT ready

  // ---- phase 2a: pull A-frags (hq) + diag B-frags before hqT is clobbered ----
  us8 hq_u[2];
#pragma unroll
  for (int sl = 0; sl < 2; ++sl)
    hq_u[sl] = *(const us8*)&hqT[(2 * w + sl) * 640 + (lane & 15) * 40 + (lane >> 4) * 8];
  us8 dg0 = *(const us8*)(dgfrag + lane * 8);
  us8 dg1 = *(const us8*)(dgfrag + (64 + lane) * 8);
  __syncthreads();   // B: hqT dead, nq region free

  // ---- phase 2b: MFMA rec+inp+decay per (s, khalf); write new_q f32 ----
  {
    f32x4 zro = {0.f, 0.f, 0.f, 0.f};
#pragma unroll
    for (int sl = 0; sl < 2; ++sl) {
      int s = 2 * w + sl;
      bf16x8 hqf = as_bf(hq_u[sl]);
#pragma unroll
      for (int kh = 0; kh < 2; ++kh) {
        us8 rwv = *(const us8*)(rwfrag + ((s * 2 + kh) * 64 + lane) * 8);
        us8 qwv = (lane < 16) ? *(const us8*)(qwfrag + ((s * 2 + kh) * 16 + lane) * 8) : z8;
        f32x4 acc = __builtin_amdgcn_mfma_f32_16x16x32_bf16(as_bf(xu), as_bf(qwv), zro, 0, 0, 0);
        acc = __builtin_amdgcn_mfma_f32_16x16x32_bf16(hqf, as_bf(rwv), acc, 0, 0, 0);
        f32x4 na;
#pragma unroll
        for (int r = 0; r < 4; ++r) na[r] = 0.1f * fast_tanh(acc[r]);
        na = __builtin_amdgcn_mfma_f32_16x16x32_bf16(hqf, as_bf(kh ? dg1 : dg0), na, 0, 0, 0);
        int k = kh * 16 + (lane & 15);
#pragma unroll
        for (int r = 0; r < 4; ++r) {
          int br = (lane >> 4) * 4 + r;
          smem[br * BST + s * SST + k] = na[r];
        }
      }
    }
  }
  __syncthreads();   // C: nq ready

  // ---- phase 3a: thread=(b,s,half): stream stable, reduce norms, write pi ----
  {
    int b3 = tid >> 5, idx = tid & 31;
    int s3 = idx >> 1, half = idx & 1;
    int base = b3 * BST + s3 * SST + half * 16;
    float ssq = 0.f, sab = 0.f;
    f32x4 zv = {0.f, 0.f, 0.f, 0.f};
#pragma unroll
    for (int q = 0; q < 4; ++q) {
      f32x4 c0 = *(const f32x4*)&smem[base + 4 * q];
      f32x4 cm = (s3 > 0)  ? *(const f32x4*)&smem[base - SST + 4 * q] : zv;
      f32x4 cp = (s3 < 15) ? *(const f32x4*)&smem[base + SST + 4 * q] : zv;
#pragma unroll
      for (int e = 0; e < 4; ++e) {
        float st = fmaf(0.04f * c0[e], cm[e] + cp[e], c0[e]);
        ssq = fmaf(st, st, ssq);
        sab += fabsf(st);
      }
    }
    ssq += __shfl_xor(ssq, 1);
    sab += __shfl_xor(sab, 1);
    float inv = __fdividef(1.0f, sqrtf(ssq) + 1e-8f);
    float energy = ssq * inv * inv;
    float mag = sab * inv;
    float pu = __fdividef(mag, energy + 1e-6f);
    float psum = pu;
#pragma unroll
    for (int m = 2; m < 32; m <<= 1) psum += __shfl_xor(psum, m);
    if (half == 0) {
      float2 pv = {__fdividef(pu, psum), inv};
      lds_pi[b3 * 16 + s3] = pv;
    }
  }
  __syncthreads();   // D: pi ready (nq untouched)

  // ---- phase 3b: thread=(b,h): streaming stable column, q_norm + output ----
  {
    const int b3 = tid >> 5, h3 = tid & 31;
    const float* colp = smem + b3 * BST + h3;
    float* qp = out + 4194304 + (((size_t)(b0 + b3) * 32) + h3) * 16;
    float prev = 0.f;
    float cur = colp[0];
    float oacc = 0.f;
    f32x4 qbuf;
#pragma unroll
    for (int s = 0; s < 16; ++s) {
      float nxt = (s < 15) ? colp[(s + 1) * SST] : 0.f;
      float st = fmaf(0.04f * cur, prev + nxt, cur);
      float2 pv = lds_pi[b3 * 16 + s];
      float q = st * pv.y;
      qbuf[s & 3] = q;
      oacc = fmaf(q, pv.x, oacc);
      if ((s & 3) == 3) *(f32x4*)(qp + (s - 3)) = qbuf;
      prev = cur; cur = nxt;
    }
    out[(size_t)(b0 + b3) * 32 + h3] = oacc;
  }
}

extern "C" void kernel_launch(void* const* d_in, const int* in_sizes, int n_in,
                              void* d_out, int out_size, void* d_ws, size_t ws_size,
                              hipStream_t stream) {
  const float* x    = (const float*)d_in[0];
  const float* hq   = (const float*)d_in[1];
  const float* qw   = (const float*)d_in[2];
  const float* rw   = (const float*)d_in[3];
  const float* tau  = (const float*)d_in[4];
  const float* syn  = (const float*)d_in[5];
  const float* corr = (const float*)d_in[6];
  unsigned short* ws = (unsigned short*)d_ws;
  unsigned short* rwfrag = ws;            // 16384 shorts
  unsigned short* qwfrag = ws + 16384;    // 4096 shorts
  unsigned short* dgfrag = ws + 20480;    // 1024 shorts
  shq_prep<<<11, 256, 0, stream>>>(qw, rw, tau, rwfrag, qwfrag, dgfrag);
  shq_main<<<B_TOTAL / NB, 512, 0, stream>>>(x, hq, syn, corr, rwfrag, qwfrag, dgfrag, (float*)d_out);
}